// Round 5
// baseline (114.169 us; speedup 1.0000x reference)
//
#include <hip/hip_runtime.h>

#define N 8192
#define D 128
// (1/0.07) * log2(e): fold temperature AND base-2 conversion into A-side scale
#define SCALE_A 20.6098592f
#define NP 64             // 8192 / 128-row panels
#define NBLK (NP * (NP + 1) / 2)   // 2080 upper-triangle panel pairs

using short8  = __attribute__((ext_vector_type(8))) short;
using float4v = __attribute__((ext_vector_type(4))) float;

#if __has_builtin(__builtin_amdgcn_exp2f)
#define EXP2(x) __builtin_amdgcn_exp2f(x)
#else
#define EXP2(x) __expf((x) * 0.69314718f)
#endif

// float -> bf16 (RNE) as raw ushort
static __device__ inline unsigned int f2bf(float f) {
    union { float f; unsigned int u; } x;
    x.f = f;
    unsigned int u = x.u;
    return (u + 0x7FFFu + ((u >> 16) & 1u)) >> 16;
}

// Pre-pass: emb fp32 -> bf16 (unscaled, B-side) and bf16*SCALE_A (A-side).
// Also zeroes tot/pos and the ticket. 65536 threads x 16 elements.
__global__ __launch_bounds__(256) void cl_prep(
    const float* __restrict__ emb, unsigned short* __restrict__ bfB,
    unsigned short* __restrict__ bfA, float* __restrict__ tot,
    int* __restrict__ ticket)
{
    const int t = blockIdx.x * 256 + threadIdx.x;
    const float* p = emb + (size_t)t * 16;
    uint4 ob[2], oa[2];
    #pragma unroll
    for (int h = 0; h < 2; ++h) {
        float4v f0 = *(const float4v*)(p + h * 8);
        float4v f1 = *(const float4v*)(p + h * 8 + 4);
        ob[h].x = f2bf(f0[0]) | (f2bf(f0[1]) << 16);
        ob[h].y = f2bf(f0[2]) | (f2bf(f0[3]) << 16);
        ob[h].z = f2bf(f1[0]) | (f2bf(f1[1]) << 16);
        ob[h].w = f2bf(f1[2]) | (f2bf(f1[3]) << 16);
        oa[h].x = f2bf(f0[0] * SCALE_A) | (f2bf(f0[1] * SCALE_A) << 16);
        oa[h].y = f2bf(f0[2] * SCALE_A) | (f2bf(f0[3] * SCALE_A) << 16);
        oa[h].z = f2bf(f1[0] * SCALE_A) | (f2bf(f1[1] * SCALE_A) << 16);
        oa[h].w = f2bf(f1[2] * SCALE_A) | (f2bf(f1[3] * SCALE_A) << 16);
    }
    ((uint4*)bfB)[t * 2]     = ob[0];
    ((uint4*)bfB)[t * 2 + 1] = ob[1];
    ((uint4*)bfA)[t * 2]     = oa[0];
    ((uint4*)bfA)[t * 2 + 1] = oa[1];
    if (t < 2 * N) tot[t] = 0.f;    // tot and pos are contiguous
    if (t == 0) *ticket = 0;
}

// Symmetric-triangle main kernel. sim = A.A^T is symmetric and the label mask
// is symmetric, so each strictly-upper element's exp contributes to BOTH its
// row sums (tot/pos[r]) and its column sums (tot/pos[c]). We launch only the
// 2080 upper panel-pairs (bi<=bj) of 128x128 tiles: half the MFMA/exp/LDS
// work of R4. 512 threads = 8 waves x (16 rows x 128 cols) — R4's proven
// no-spill wave tile. One 32KB B-tile per block, staged ONCE via
// global_load_lds + involution swizzle (4x fewer stage stalls than R4).
// Col partials are lane-local (col = lane&15): 2x shfl_xor + 16 coalesced
// atomic instructions per wave. Diag blocks: skip tiles tc<wave, strict r<c
// mask on tc==wave. Reduction/finalize = proven ticket path.
__global__ __launch_bounds__(512, 4) void cl_main(
    const unsigned short* __restrict__ bfA, const unsigned short* __restrict__ bfB,
    const int* __restrict__ labels,
    float* __restrict__ tot, float* __restrict__ pos,
    int* __restrict__ ticket, float* __restrict__ out)
{
    __shared__ uint4 ldsB[128 * 16];   // 32KB, single buffer, swizzled image
    __shared__ float sred[2][8];
    __shared__ int   s_ticket;

    const int tid  = threadIdx.x;
    const int lane = tid & 63;
    const int wave = tid >> 6;    // 0..7 = this wave's 16-row strip
    const int q    = lane >> 4;   // quad id 0..3
    const int c    = lane & 15;

    // ---- decode upper-triangle panel pair (bi <= bj) from 1D block id ----
    const int k = blockIdx.x;
    int bi = (int)((129.0f - sqrtf(16641.0f - 8.0f * (float)k)) * 0.5f);
    while (bi * (129 - bi) / 2 > k) --bi;                  // integer correction
    while ((bi + 1) * (128 - bi) / 2 <= k) ++bi;
    const int bj = bi + (k - bi * (129 - bi) / 2);
    const int R0 = bi * 128, C0 = bj * 128;
    const bool diagblk = (bi == bj);

    // ---- stage B-tile (cols C0..C0+128) once: DMA, pre-swizzled source ----
    const uint4* src = (const uint4*)bfB + (size_t)C0 * 16;
    #pragma unroll
    for (int i = 0; i < 4; ++i) {
        const int g     = tid + i * 512;
        const int row   = g >> 4;
        const int chunk = g & 15;
        __builtin_amdgcn_global_load_lds(
            (const __attribute__((address_space(1))) void*)(src + row * 16 + (chunk ^ (row & 15))),
            (__attribute__((address_space(3))) void*)(&ldsB[g]),
            16, 0, 0);
    }

    // ---- A fragments + labels (global, L2-hit) while the DMA flies ----
    short8 afrag[4];
    int rowlab[4], collab[8];
    {
        const int arow = R0 + wave * 16 + c;
        #pragma unroll
        for (int ks = 0; ks < 4; ++ks)
            afrag[ks] = *(const short8*)(bfA + (size_t)arow * D + ks * 32 + q * 8);
        #pragma unroll
        for (int reg = 0; reg < 4; ++reg)
            rowlab[reg] = labels[R0 + wave * 16 + q * 4 + reg];
        #pragma unroll
        for (int tc = 0; tc < 8; ++tc)
            collab[tc] = labels[C0 + tc * 16 + c];
    }

    asm volatile("s_waitcnt vmcnt(0)" ::: "memory");   // DMA + frags complete
    __builtin_amdgcn_s_barrier();
    __builtin_amdgcn_sched_barrier(0);

    // ---- MFMA: 1 tile-row x 8 tile-cols, K=128 in 4 steps ----
    float4v acc[8];
    #pragma unroll
    for (int tc = 0; tc < 8; ++tc) {
        float4v z = {0.f, 0.f, 0.f, 0.f};
        acc[tc] = z;
    }
    const short8* ldsS = (const short8*)ldsB;
    #pragma unroll
    for (int ks = 0; ks < 4; ++ks) {
        const short8* pk = ldsS + c * 16 + ((ks * 4 + q) ^ c);
        #pragma unroll
        for (int tc = 0; tc < 8; ++tc) {
            if (diagblk && tc < wave) continue;        // wave-uniform skip
            short8 b = pk[tc * 256];
            acc[tc] = __builtin_amdgcn_mfma_f32_16x16x32_bf16(
                afrag[ks], b, acc[tc], 0, 0, 0);
        }
    }

    // ---- epilogue: exp2 once, accumulate into row AND column partials ----
    float tot_a[4] = {0.f, 0.f, 0.f, 0.f};
    float pos_a[4] = {0.f, 0.f, 0.f, 0.f};
    float ctot[8]  = {0.f, 0.f, 0.f, 0.f, 0.f, 0.f, 0.f, 0.f};
    float cpos[8]  = {0.f, 0.f, 0.f, 0.f, 0.f, 0.f, 0.f, 0.f};
    #pragma unroll
    for (int tc = 0; tc < 8; ++tc) {
        if (diagblk && tc < wave) continue;            // mirrored by tile (tc,wave)
        const int lc = collab[tc];
        if (diagblk && tc == wave) {
            // diagonal 16x16 tile: keep strictly-upper (r<c); r==c excluded,
            // r>c covered by its mirror element inside this same tile.
            #pragma unroll
            for (int reg = 0; reg < 4; ++reg) {
                float v = EXP2(acc[tc][reg]);
                if ((q * 4 + reg) >= c) v = 0.f;
                tot_a[reg] += v;  ctot[tc] += v;
                if (rowlab[reg] == lc) { pos_a[reg] += v; cpos[tc] += v; }
            }
        } else {
            #pragma unroll
            for (int reg = 0; reg < 4; ++reg) {
                float v = EXP2(acc[tc][reg]);
                tot_a[reg] += v;  ctot[tc] += v;
                if (rowlab[reg] == lc) { pos_a[reg] += v; cpos[tc] += v; }
            }
        }
    }

    // ---- row reduction over the 16 column-lanes, one atomic per row ----
    #pragma unroll
    for (int reg = 0; reg < 4; ++reg) {
        float t = tot_a[reg];
        float p = pos_a[reg];
        #pragma unroll
        for (int m = 1; m < 16; m <<= 1) {
            t += __shfl_xor(t, m, 64);
            p += __shfl_xor(p, m, 64);
        }
        if (c == 0) {
            const int r = R0 + wave * 16 + q * 4 + reg;
            atomicAdd(&tot[r], t);   // device-scope RMW at coherent point
            atomicAdd(&pos[r], p);
        }
    }

    // ---- column reduction over the 4 q-groups, coalesced atomics ----
    #pragma unroll
    for (int tc = 0; tc < 8; ++tc) {
        if (diagblk && tc < wave) continue;            // partials are zero anyway
        float t = ctot[tc], p = cpos[tc];
        t += __shfl_xor(t, 16, 64);  t += __shfl_xor(t, 32, 64);
        p += __shfl_xor(p, 16, 64);  p += __shfl_xor(p, 32, 64);
        if (q == 0) {
            const int cc = C0 + tc * 16 + c;           // lanes 0..15: coalesced
            atomicAdd(&tot[cc], t);
            atomicAdd(&pos[cc], p);
        }
    }

    // ---- last-block finalize: completion-wait + relaxed ticket (NO cache ops)
    asm volatile("s_waitcnt vmcnt(0)" ::: "memory");  // our atomics committed
    __syncthreads();
    if (tid == 0)
        s_ticket = __hip_atomic_fetch_add(ticket, 1, __ATOMIC_RELAXED,
                                          __HIP_MEMORY_SCOPE_AGENT);
    __syncthreads();
    if (s_ticket != NBLK - 1) return;

    float lsum = 0.f, lcnt = 0.f;
    #pragma unroll 4
    for (int i = tid; i < N; i += 512) {
        const float t = __hip_atomic_load(&tot[i], __ATOMIC_RELAXED,
                                          __HIP_MEMORY_SCOPE_AGENT);
        const float p = __hip_atomic_load(&pos[i], __ATOMIC_RELAXED,
                                          __HIP_MEMORY_SCOPE_AGENT);
        const float loss = -__logf(p / (t + 1e-8f) + 1e-8f);
        if (p > 0.f) { lsum += loss; lcnt += 1.f; }   // valid <=> pos>0
    }
    #pragma unroll
    for (int m = 1; m < 64; m <<= 1) {
        lsum += __shfl_xor(lsum, m, 64);
        lcnt += __shfl_xor(lcnt, m, 64);
    }
    if (lane == 0) { sred[0][wave] = lsum; sred[1][wave] = lcnt; }
    __syncthreads();
    if (tid == 0) {
        float s = 0.f, n = 0.f;
        #pragma unroll
        for (int w = 0; w < 8; ++w) { s += sred[0][w]; n += sred[1][w]; }
        out[0] = (n > 0.f) ? s / fmaxf(n, 1.f) : 0.f;
    }
}

extern "C" void kernel_launch(void* const* d_in, const int* in_sizes, int n_in,
                              void* d_out, int out_size, void* d_ws, size_t ws_size,
                              hipStream_t stream) {
    const float* emb  = (const float*)d_in[0];
    const int* labels = (const int*)d_in[1];
    unsigned short* bfB = (unsigned short*)d_ws;                       // 2 MB
    unsigned short* bfA = bfB + (size_t)N * D;                         // 2 MB
    float* tot    = (float*)(bfA + (size_t)N * D);
    float* pos    = tot + N;
    int*   ticket = (int*)(pos + N);

    cl_prep<<<256, 256, 0, stream>>>(emb, bfB, bfA, tot, ticket);
    cl_main<<<NBLK, 512, 0, stream>>>(bfA, bfB, labels, tot, pos,
                                      ticket, (float*)d_out);
}

// Round 6
// 97.266 us; speedup vs baseline: 1.1738x; 1.1738x over previous
//
#include <hip/hip_runtime.h>

#define N 8192
#define D 128
// (1/0.07) * log2(e): fold temperature AND base-2 conversion into A-side scale
#define SCALE_A 20.6098592f
#define NP 64             // 8192 / 128-row panels
#define NBLK 512          // 64 panels x 8 m-chunks
#define NBLK_PREP 256

using short8  = __attribute__((ext_vector_type(8))) short;
using float4v = __attribute__((ext_vector_type(4))) float;

#if __has_builtin(__builtin_amdgcn_exp2f)
#define EXP2(x) __builtin_amdgcn_exp2f(x)
#else
#define EXP2(x) __expf((x) * 0.69314718f)
#endif

// float -> bf16 (RNE) as raw ushort
static __device__ inline unsigned int f2bf(float f) {
    union { float f; unsigned int u; } x;
    x.f = f;
    unsigned int u = x.u;
    return (u + 0x7FFFu + ((u >> 16) & 1u)) >> 16;
}

// Pre-pass: emb fp32 -> bf16 (unscaled, B-side) and bf16*SCALE_A (A-side).
// Also zeroes tot/pos and the ticket. 65536 threads x 16 elements.
__global__ __launch_bounds__(256) void cl_prep(
    const float* __restrict__ emb, unsigned short* __restrict__ bfB,
    unsigned short* __restrict__ bfA, float* __restrict__ tot,
    int* __restrict__ ticket)
{
    const int t = blockIdx.x * 256 + threadIdx.x;
    const float* p = emb + (size_t)t * 16;
    uint4 ob[2], oa[2];
    #pragma unroll
    for (int h = 0; h < 2; ++h) {
        float4v f0 = *(const float4v*)(p + h * 8);
        float4v f1 = *(const float4v*)(p + h * 8 + 4);
        ob[h].x = f2bf(f0[0]) | (f2bf(f0[1]) << 16);
        ob[h].y = f2bf(f0[2]) | (f2bf(f0[3]) << 16);
        ob[h].z = f2bf(f1[0]) | (f2bf(f1[1]) << 16);
        ob[h].w = f2bf(f1[2]) | (f2bf(f1[3]) << 16);
        oa[h].x = f2bf(f0[0] * SCALE_A) | (f2bf(f0[1] * SCALE_A) << 16);
        oa[h].y = f2bf(f0[2] * SCALE_A) | (f2bf(f0[3] * SCALE_A) << 16);
        oa[h].z = f2bf(f1[0] * SCALE_A) | (f2bf(f1[1] * SCALE_A) << 16);
        oa[h].w = f2bf(f1[2] * SCALE_A) | (f2bf(f1[3] * SCALE_A) << 16);
    }
    ((uint4*)bfB)[t * 2]     = ob[0];
    ((uint4*)bfB)[t * 2 + 1] = ob[1];
    ((uint4*)bfA)[t * 2]     = oa[0];
    ((uint4*)bfA)[t * 2 + 1] = oa[1];
    if (t < 2 * N) tot[t] = 0.f;    // tot and pos are contiguous
    if (t == 0) *ticket = 0;
}

// Symmetric main kernel, diagonal-wrap decomposition. sim = A.A^T and the
// label mask are symmetric, so each unordered 128x128 panel pair is computed
// ONCE and its exp contributes to BOTH row sums (panel i, registers) and
// column sums (panel j, per-iter coalesced atomics). Pair coverage: block
// (i, cid) handles j=(i+m)&63 for m in {4cid..4cid+3}; m=32 is double-
// covered so only i<32 runs it (appended to cid 0). 64x4x8 + 32 = 2080
// tiles = the full upper triangle, exactly once (R5 verified the mirror
// math bit-exact; R5's failure was 1 tile/block overhead, fixed here with
// 4-5 tiles/block at R4's proven no-spill 16-row wave shape).
__global__ __launch_bounds__(512, 4) void cl_main(
    const unsigned short* __restrict__ bfA, const unsigned short* __restrict__ bfB,
    const int* __restrict__ labels,
    float* __restrict__ tot, float* __restrict__ pos,
    int* __restrict__ ticket, float* __restrict__ out)
{
    __shared__ uint4 ldsB[128 * 16];   // 32KB, single buffer, swizzled image
    __shared__ float sred[2][8];
    __shared__ int   s_ticket;

    const int tid  = threadIdx.x;
    const int lane = tid & 63;
    const int wave = tid >> 6;    // 0..7 = this wave's 16-row strip
    const int q    = lane >> 4;   // quad id 0..3
    const int c    = lane & 15;

    const int i   = blockIdx.x >> 3;   // row panel 0..63
    const int cid = blockIdx.x & 7;    // m-chunk
    const int nit = (cid == 0 && i < 32) ? 5 : 4;
    const int R0r = i * 128;
    const uint4* bfB4 = (const uint4*)bfB;

    // ---- stage tile for iter 0 (m = 4*cid) ----
    int m0 = cid * 4;
    {
        const uint4* src = bfB4 + (size_t)(((i + m0) & 63) * 128) * 16;
        #pragma unroll
        for (int s = 0; s < 4; ++s) {
            const int g     = tid + s * 512;
            const int row   = g >> 4;
            const int chunk = g & 15;
            __builtin_amdgcn_global_load_lds(
                (const __attribute__((address_space(1))) void*)(src + row * 16 + (chunk ^ (row & 15))),
                (__attribute__((address_space(3))) void*)(&ldsB[g]),
                16, 0, 0);
        }
    }

    // ---- A fragments + row labels, once per block ----
    short8 afrag[4];
    int rowlab[4];
    {
        const int arow = R0r + wave * 16 + c;
        #pragma unroll
        for (int ks = 0; ks < 4; ++ks)
            afrag[ks] = *(const short8*)(bfA + (size_t)arow * D + ks * 32 + q * 8);
        #pragma unroll
        for (int reg = 0; reg < 4; ++reg)
            rowlab[reg] = labels[R0r + wave * 16 + q * 4 + reg];
    }
    int collab[8];
    #pragma unroll
    for (int tc = 0; tc < 8; ++tc)
        collab[tc] = labels[((i + m0) & 63) * 128 + tc * 16 + c];

    asm volatile("s_waitcnt vmcnt(0) lgkmcnt(0)" ::: "memory");
    __builtin_amdgcn_s_barrier();
    __builtin_amdgcn_sched_barrier(0);

    float tot_a[4] = {0.f, 0.f, 0.f, 0.f};   // row partials, panel i (persist)
    float pos_a[4] = {0.f, 0.f, 0.f, 0.f};

    #pragma unroll 1
    for (int it = 0; it < nit; ++it) {
        const int m    = (cid == 0) ? ((it == 4) ? 32 : it) : (cid * 4 + it);
        const int j    = (i + m) & 63;
        const int C0   = j * 128;
        const bool diag = (m == 0);

        // ---- MFMA: 1 tile-row x 8 tile-cols, K=128 in 4 steps ----
        float4v acc[8];
        #pragma unroll
        for (int tc = 0; tc < 8; ++tc) {
            float4v z = {0.f, 0.f, 0.f, 0.f};
            acc[tc] = z;
        }
        const short8* ldsS = (const short8*)ldsB;
        #pragma unroll
        for (int ks = 0; ks < 4; ++ks) {
            const short8* pk = ldsS + c * 16 + ((ks * 4 + q) ^ c);
            #pragma unroll
            for (int tc = 0; tc < 8; ++tc) {
                if (diag && tc < wave) continue;       // wave-uniform skip
                short8 b = pk[tc * 256];
                acc[tc] = __builtin_amdgcn_mfma_f32_16x16x32_bf16(
                    afrag[ks], b, acc[tc], 0, 0, 0);
            }
        }

        // ---- epilogue: exp2 once, accumulate rows AND mirrored columns ----
        float ctot[8] = {0,0,0,0,0,0,0,0};
        float cpos[8] = {0,0,0,0,0,0,0,0};
        #pragma unroll
        for (int tc = 0; tc < 8; ++tc) {
            if (diag && tc < wave) continue;           // covered by mirror tile
            const int lc = collab[tc];
            if (diag && tc == wave) {
                // diagonal 16x16: keep strictly-upper r<c; r==c excluded,
                // r>c is this tile's own mirror.
                #pragma unroll
                for (int reg = 0; reg < 4; ++reg) {
                    float v = EXP2(acc[tc][reg]);
                    if ((q * 4 + reg) >= c) v = 0.f;
                    tot_a[reg] += v;  ctot[tc] += v;
                    if (rowlab[reg] == lc) { pos_a[reg] += v; cpos[tc] += v; }
                }
            } else {
                #pragma unroll
                for (int reg = 0; reg < 4; ++reg) {
                    float v = EXP2(acc[tc][reg]);
                    tot_a[reg] += v;  ctot[tc] += v;
                    if (rowlab[reg] == lc) { pos_a[reg] += v; cpos[tc] += v; }
                }
            }
        }

        // ---- flush column partials for panel j: 2x shfl + coalesced atomics
        #pragma unroll
        for (int tc = 0; tc < 8; ++tc) {
            if (diag && tc < wave) continue;           // zero partials
            float t = ctot[tc], p = cpos[tc];
            t += __shfl_xor(t, 16, 64);  t += __shfl_xor(t, 32, 64);
            p += __shfl_xor(p, 16, 64);  p += __shfl_xor(p, 32, 64);
            if (q == 0) {
                const int cc = C0 + tc * 16 + c;       // lanes 0..15 coalesced
                atomicAdd(&tot[cc], t);
                atomicAdd(&pos[cc], p);
            }
        }

        __builtin_amdgcn_sched_barrier(0);
        __builtin_amdgcn_s_barrier();                  // ldsB reads done
        __builtin_amdgcn_sched_barrier(0);

        if (it < nit - 1) {
            const int mn = (cid == 0) ? ((it + 1 == 4) ? 32 : it + 1)
                                      : (cid * 4 + it + 1);
            const int jn = (i + mn) & 63;
            const uint4* src = bfB4 + (size_t)(jn * 128) * 16;
            #pragma unroll
            for (int s = 0; s < 4; ++s) {
                const int g     = tid + s * 512;
                const int row   = g >> 4;
                const int chunk = g & 15;
                __builtin_amdgcn_global_load_lds(
                    (const __attribute__((address_space(1))) void*)(src + row * 16 + (chunk ^ (row & 15))),
                    (__attribute__((address_space(3))) void*)(&ldsB[g]),
                    16, 0, 0);
            }
            #pragma unroll
            for (int tc = 0; tc < 8; ++tc)
                collab[tc] = labels[jn * 128 + tc * 16 + c];
            asm volatile("s_waitcnt vmcnt(0)" ::: "memory");
            __builtin_amdgcn_s_barrier();              // next tile visible
            __builtin_amdgcn_sched_barrier(0);
        }
    }

    // ---- row reduction over the 16 column-lanes, one atomic per row ----
    #pragma unroll
    for (int reg = 0; reg < 4; ++reg) {
        float t = tot_a[reg];
        float p = pos_a[reg];
        #pragma unroll
        for (int m = 1; m < 16; m <<= 1) {
            t += __shfl_xor(t, m, 64);
            p += __shfl_xor(p, m, 64);
        }
        if (c == 0) {
            const int r = R0r + wave * 16 + q * 4 + reg;
            atomicAdd(&tot[r], t);   // device-scope RMW at coherent point
            atomicAdd(&pos[r], p);
        }
    }

    // ---- last-block finalize: completion-wait + relaxed ticket (NO cache ops)
    asm volatile("s_waitcnt vmcnt(0)" ::: "memory");  // our atomics committed
    __syncthreads();
    if (tid == 0)
        s_ticket = __hip_atomic_fetch_add(ticket, 1, __ATOMIC_RELAXED,
                                          __HIP_MEMORY_SCOPE_AGENT);
    __syncthreads();
    if (s_ticket != NBLK - 1) return;

    float lsum = 0.f, lcnt = 0.f;
    #pragma unroll 4
    for (int idx = tid; idx < N; idx += 512) {
        const float t = __hip_atomic_load(&tot[idx], __ATOMIC_RELAXED,
                                          __HIP_MEMORY_SCOPE_AGENT);
        const float p = __hip_atomic_load(&pos[idx], __ATOMIC_RELAXED,
                                          __HIP_MEMORY_SCOPE_AGENT);
        const float loss = -__logf(p / (t + 1e-8f) + 1e-8f);
        if (p > 0.f) { lsum += loss; lcnt += 1.f; }   // valid <=> pos>0
    }
    #pragma unroll
    for (int m = 1; m < 64; m <<= 1) {
        lsum += __shfl_xor(lsum, m, 64);
        lcnt += __shfl_xor(lcnt, m, 64);
    }
    if (lane == 0) { sred[0][wave] = lsum; sred[1][wave] = lcnt; }
    __syncthreads();
    if (tid == 0) {
        float s = 0.f, n = 0.f;
        #pragma unroll
        for (int w = 0; w < 8; ++w) { s += sred[0][w]; n += sred[1][w]; }
        out[0] = (n > 0.f) ? s / fmaxf(n, 1.f) : 0.f;
    }
}

extern "C" void kernel_launch(void* const* d_in, const int* in_sizes, int n_in,
                              void* d_out, int out_size, void* d_ws, size_t ws_size,
                              hipStream_t stream) {
    const float* emb  = (const float*)d_in[0];
    const int* labels = (const int*)d_in[1];
    unsigned short* bfB = (unsigned short*)d_ws;                       // 2 MB
    unsigned short* bfA = bfB + (size_t)N * D;                         // 2 MB
    float* tot    = (float*)(bfA + (size_t)N * D);
    float* pos    = tot + N;
    int*   ticket = (int*)(pos + N);

    cl_prep<<<NBLK_PREP, 256, 0, stream>>>(emb, bfB, bfA, tot, ticket);
    cl_main<<<NBLK, 512, 0, stream>>>(bfA, bfB, labels, tot, pos,
                                      ticket, (float*)d_out);
}